// Round 3
// baseline (164.161 us; speedup 1.0000x reference)
//
#include <hip/hip_runtime.h>
#include <math.h>

#define S_LEN 2048
#define B_SZ 2
#define NH 8
#define DH 64
#define DM 512
#define MROWS 4096  // B*S

typedef __attribute__((ext_vector_type(8))) short s16x8;
typedef __attribute__((ext_vector_type(4))) float fx4;
typedef __attribute__((ext_vector_type(16))) float fx16;
typedef __attribute__((ext_vector_type(4))) int ix4;

__device__ inline short f2bf(float x){
  unsigned u = __float_as_uint(x);
  u = (u + 0x7FFFu + ((u >> 16) & 1u)) >> 16;
  return (short)u;
}

__device__ inline fx4 mfma16(s16x8 a, s16x8 b, fx4 c){
  return __builtin_amdgcn_mfma_f32_16x16x32_bf16(a, b, c, 0, 0, 0);
}
__device__ inline fx16 mfma32(s16x8 a, s16x8 b, fx16 c){
  return __builtin_amdgcn_mfma_f32_32x32x16_bf16(a, b, c, 0, 0, 0);
}
__device__ inline int cvtpk(float a, float b){
  int r; asm("v_cvt_pk_bf16_f32 %0, %1, %2" : "=v"(r) : "v"(a), "v"(b)); return r;
}

#define GLL16(g, l) __builtin_amdgcn_global_load_lds((const __attribute__((address_space(1))) void*)(g), (__attribute__((address_space(3))) void*)(l), 16, 0, 0)
#define GLL4(g, l)  __builtin_amdgcn_global_load_lds((const __attribute__((address_space(1))) void*)(g), (__attribute__((address_space(3))) void*)(l), 4, 0, 0)

// ---- K0: f32 weight (K=512, N=512) -> bf16 transposed (N,K) ----
__global__ __launch_bounds__(256) void wt_kernel(const float* __restrict__ W,
                                                 short* __restrict__ Wt){
  __shared__ short tile[64][66];
  int n0 = blockIdx.x * 64, k0 = blockIdx.y * 64;
  int t = threadIdx.x;
  int nl = t & 63;
  #pragma unroll
  for (int p = 0; p < 16; ++p){
    int kl = (t >> 6) + p * 4;
    tile[kl][nl] = f2bf(W[(size_t)(k0 + kl) * DM + n0 + nl]);
  }
  __syncthreads();
  int kl2 = t & 63;
  #pragma unroll
  for (int p = 0; p < 16; ++p){
    int nl2 = (t >> 6) + p * 4;
    Wt[(size_t)(n0 + nl2) * DM + k0 + kl2] = tile[kl2][nl2];
  }
}

// ---- K1: Lorentz log map at origin (K=-1) ----
__global__ __launch_bounds__(128) void logmap_kernel(const float* __restrict__ x,
                                                     short* __restrict__ xeu){
  int row = blockIdx.x;
  const float* xr = x + (size_t)row * (DM + 1);
  int t = threadIdx.x;
  float v[4]; float ss = 0.f;
  #pragma unroll
  for (int j = 0; j < 4; ++j){
    v[j] = xr[1 + t + 128 * j];
    ss += v[j] * v[j];
  }
  #pragma unroll
  for (int off = 1; off < 64; off <<= 1) ss += __shfl_xor(ss, off);
  __shared__ float s2[2];
  if ((t & 63) == 0) s2[t >> 6] = ss;
  __syncthreads();
  float tot = s2[0] + s2[1];
  float nrm = sqrtf(tot);
  float xt = xr[0];
  float theta = acoshf(fmaxf(xt, 1.0f + 1e-7f));
  float scl = theta / fmaxf(nrm, 1e-7f);
  #pragma unroll
  for (int j = 0; j < 4; ++j)
    xeu[(size_t)row * DM + t + 128 * j] = f2bf(scl * v[j]);
}

// ---- K2/K5: LDS-staged GEMM  C(M,512) f32 = A(M,512)bf16 @ Bt(512n,512k)^T ----
// tile 128m x 64n, BK=64, 4 waves (2x2), double-buffered global_load_lds.
__global__ __launch_bounds__(256, 3) void gemm_kernel(const short* __restrict__ A,
                                                      const short* __restrict__ Bt,
                                                      float* __restrict__ C){
  __shared__ __attribute__((aligned(16))) short Asm[2][128 * 64];
  __shared__ __attribute__((aligned(16))) short Bsm[2][64 * 64];
  const int K = DM;
  int z = blockIdx.z;
  Bt += (size_t)z * K * DM;
  C  += (size_t)z * (size_t)MROWS * DM;
  int n0 = blockIdx.x * 64, m0 = blockIdx.y * 128;
  int t = threadIdx.x;
  int w = t >> 6, lane = t & 63;
  int wm = w >> 1, wn = w & 1;
  int lg = lane >> 4, lr = lane & 15;

  // staging descriptors: A 4 chunks/thread, B 2 chunks/thread (16B chunks)
  int aoff[4]; const short* asrcp[4];
  int boff[2]; const short* bsrcp[2];
  #pragma unroll
  for (int j = 0; j < 4; ++j){
    int ch = t + 256 * j;
    int r = ch >> 3, c = ch & 7;
    aoff[j] = ch * 8;
    asrcp[j] = A + (size_t)(m0 + r) * K + 8 * (c ^ (r & 7));
  }
  #pragma unroll
  for (int j = 0; j < 2; ++j){
    int ch = t + 256 * j;
    int r = ch >> 3, c = ch & 7;
    boff[j] = ch * 8;
    bsrcp[j] = Bt + (size_t)(n0 + r) * K + 8 * (c ^ (r & 7));
  }

  // prologue: stage k-step 0 into buf 0
  {
    short* ab = &Asm[0][0]; short* bb = &Bsm[0][0];
    #pragma unroll
    for (int j = 0; j < 4; ++j) GLL16(asrcp[j], ab + aoff[j]);
    #pragma unroll
    for (int j = 0; j < 2; ++j) GLL16(bsrcp[j], bb + boff[j]);
  }

  fx4 acc[4][2] = {};
  int buf = 0;
  for (int ks = 0; ks < 8; ++ks){
    if (ks < 7){
      int nb = buf ^ 1;
      short* ab = &Asm[nb][0]; short* bb = &Bsm[nb][0];
      int kk = (ks + 1) * 64;
      #pragma unroll
      for (int j = 0; j < 4; ++j) GLL16(asrcp[j] + kk, ab + aoff[j]);
      #pragma unroll
      for (int j = 0; j < 2; ++j) GLL16(bsrcp[j] + kk, bb + boff[j]);
      asm volatile("s_waitcnt vmcnt(6)" ::: "memory");
    } else {
      asm volatile("s_waitcnt vmcnt(0)" ::: "memory");
    }
    __builtin_amdgcn_s_barrier();

    s16x8 af[4][2], bf[2][2];
    #pragma unroll
    for (int mi = 0; mi < 4; ++mi){
      int row = wm * 64 + mi * 16 + lr;
      #pragma unroll
      for (int s = 0; s < 2; ++s)
        af[mi][s] = *(const s16x8*)&Asm[buf][row * 64 + ((4 * s + lg) ^ (row & 7)) * 8];
    }
    #pragma unroll
    for (int ni = 0; ni < 2; ++ni){
      int row = wn * 32 + ni * 16 + lr;
      #pragma unroll
      for (int s = 0; s < 2; ++s)
        bf[ni][s] = *(const s16x8*)&Bsm[buf][row * 64 + ((4 * s + lg) ^ (row & 7)) * 8];
    }
    #pragma unroll
    for (int s = 0; s < 2; ++s)
      #pragma unroll
      for (int mi = 0; mi < 4; ++mi)
        #pragma unroll
        for (int ni = 0; ni < 2; ++ni)
          acc[mi][ni] = mfma16(af[mi][s], bf[ni][s], acc[mi][ni]);
    __builtin_amdgcn_s_barrier();
    buf ^= 1;
  }

  #pragma unroll
  for (int mi = 0; mi < 4; ++mi)
    #pragma unroll
    for (int ni = 0; ni < 2; ++ni)
      #pragma unroll
      for (int r = 0; r < 4; ++r){
        int row = m0 + wm * 64 + mi * 16 + 4 * lg + r;
        int col = n0 + wn * 32 + ni * 16 + lr;
        C[(size_t)row * DM + col] = acc[mi][ni][r];
      }
}

// ---- K3: per-head exp map + score folding (log2e folded into a) ----
__global__ __launch_bounds__(256) void expmap_kernel(const float* __restrict__ Q,
                                                     const float* __restrict__ Kp,
                                                     const float* __restrict__ labsK,
                                                     float* __restrict__ Qt,
                                                     short* __restrict__ Qs,
                                                     float* __restrict__ Kt,
                                                     short* __restrict__ Ks){
  int idx = blockIdx.x * 4 + (threadIdx.x >> 6);   // (b*S+s)*H + h
  int d = threadIdx.x & 63;
  int h = idx & (NH - 1);
  int bs = idx >> 3;
  int s = bs & (S_LEN - 1);
  int b = bs >> 11;
  float c  = __expf(labsK[h]);
  float sc = sqrtf(c);
  float a  = 0.125f * c * 1.4426950408889634f;   // fold log2(e): softmax uses exp2
  size_t bhs = ((size_t)(b * NH + h) * S_LEN + s);

  float qv = Q[(size_t)idx * DH + d];
  float ssq = qv * qv;
  #pragma unroll
  for (int off = 1; off < 64; off <<= 1) ssq += __shfl_xor(ssq, off);
  float nq = fmaxf(sqrtf(ssq), 1e-7f);
  float argq = sc * nq;
  float eq = __expf(argq), eqi = __frcp_rn(eq);
  if (d == 0) Qt[bhs] = a * 0.5f * (eq + eqi) / sc;
  float qscale = -a * 0.5f * (eq - eqi) / argq;
  Qs[bhs * DH + d] = f2bf(qscale * qv);

  float kv = Kp[(size_t)idx * DH + d];
  float ksq = kv * kv;
  #pragma unroll
  for (int off = 1; off < 64; off <<= 1) ksq += __shfl_xor(ksq, off);
  float nk = fmaxf(sqrtf(ksq), 1e-7f);
  float argk = sc * nk;
  float ek = __expf(argk), eki = __frcp_rn(ek);
  if (d == 0) Kt[bhs] = 0.5f * (ek + eki) / sc;
  float kscale = 0.5f * (ek - eki) / argk;
  Ks[bhs * DH + d] = f2bf(kscale * kv);
}

// ---- K3b: V (b,s,h,d) f32 -> Vt (b,h,d,s) bf16 ----
__global__ __launch_bounds__(256) void vtrans_kernel(const float* __restrict__ V,
                                                     short* __restrict__ Vt){
  __shared__ short tile[64][66];
  int s0 = blockIdx.x * 64;
  int bh = blockIdx.y;
  int b = bh >> 3, h = bh & 7;
  int t = threadIdx.x;
  int dl = t & 63;
  #pragma unroll
  for (int p = 0; p < 16; ++p){
    int sl = (t >> 6) + p * 4;
    tile[sl][dl] = f2bf(V[((size_t)b * S_LEN + s0 + sl) * DM + h * DH + dl]);
  }
  __syncthreads();
  int sl2 = t & 63;
  #pragma unroll
  for (int p = 0; p < 16; ++p){
    int dl2 = (t >> 6) + p * 4;
    Vt[((size_t)bh * DH + dl2) * S_LEN + s0 + sl2] = tile[sl2][dl2];
  }
}

// ---- K4: flash attention, key-split chunks for balance+occupancy.
// grid 640: bh = bx&15, id = bx>>4 -> (qgroup g, key-chunk c). 4 waves x 32q.
// Emits per-chunk partials (m, l, O^T f32); combine_kernel merges.
__global__ __launch_bounds__(256, 4) void attn_kernel(const short* __restrict__ Qs,
                                                      const float* __restrict__ Qt,
                                                      const short* __restrict__ Ks,
                                                      const float* __restrict__ Kt,
                                                      const short* __restrict__ Vt,
                                                      float* __restrict__ Mpart,
                                                      float* __restrict__ Lpart,
                                                      float* __restrict__ Opart){
  __shared__ __attribute__((aligned(16))) short Ksm[2][4096];
  __shared__ __attribute__((aligned(16))) short Vsm[2][4096];
  __shared__ __attribute__((aligned(16))) float Ktm[2][64];

  int bx = blockIdx.x;
  int bh = bx & 15;                 // XCD-local heads
  int id = bx >> 4;                 // 0..39
  int g, c;
  if (id < 4)       { g = id;                 c = 0; }
  else if (id < 12) { g = 4 + ((id - 4) >> 1);  c = (id - 4) & 1; }
  else if (id < 24) { int r = id - 12; int q3 = r / 3; g = 8 + q3; c = r - 3 * q3; }
  else              { g = 12 + ((id - 24) >> 2); c = (id - 24) & 3; }
  int kbeg = 512 * c;
  int kend = 512 * c + 512; { int ge = 128 * g + 128; if (ge < kend) kend = ge; }
  int ntc = (kend - kbeg) >> 6;

  int tid = threadIdx.x;
  int w = tid >> 6, lane = tid & 63;
  int l5 = lane & 31, hi = lane >> 5;
  size_t bhS = (size_t)bh * S_LEN;

  const short* Kg  = Ks + bhS * DH;
  const short* Vg  = Vt + (size_t)bh * DH * S_LEN;
  const float* Ktg = Kt + bhS;

  // staging source addresses (XOR-swizzled global side; LDS dest linear)
  int srow = lane >> 3;                                // 0..7
  int scol = ((lane & 7) * 8) ^ (srow << 3);           // swizzled 16B granule
  const short* kg0 = Kg + (size_t)(kbeg + 16 * w + srow) * DH + scol;
  const short* kg1 = kg0 + 8 * DH;
  const short* vg0 = Vg + (size_t)(16 * w + srow) * S_LEN + kbeg + scol;
  const short* vg1 = vg0 + 8 * S_LEN;
  const float* ktg = Ktg + kbeg + lane;
  short* Kd0 = &Ksm[0][16 * w * 64]; short* Kd1 = Kd0 + 512;
  short* Vd0 = &Vsm[0][16 * w * 64]; short* Vd1 = Vd0 + 512;

  // Q fragments (B operand: col=q=lane&31, k(d)=8*hi+j)
  int q0w = 128 * g + 32 * w;
  int q   = q0w + l5;
  int qmax = q0w + 31;
  s16x8 qf[4];
  #pragma unroll
  for (int dblk = 0; dblk < 4; ++dblk)
    qf[dblk] = *(const s16x8*)(Qs + (bhS + q) * DH + dblk * 16 + hi * 8);
  float aqt = Qt[bhS + q];

  fx16 acc0, acc1;
  #pragma unroll
  for (int i = 0; i < 16; ++i){ acc0[i] = 0.f; acc1[i] = 0.f; }
  float mrun = 0.f, lrun = 0.f;

  // prologue: stage tile 0 into buf 0
  GLL16(kg0, Kd0); GLL16(kg1, Kd1);
  GLL16(vg0, Vd0); GLL16(vg1, Vd1);
  if (w == 3) GLL4(ktg, &Ktm[0][0]);
  int buf = 0;

  for (int t = 0; t < ntc; ++t){
    int k0 = kbeg + t * 64;
    if (t + 1 < ntc){
      int off = (t + 1) * 64;
      int bn = buf ^ 1;
      GLL16(kg0 + (size_t)off * DH, &Ksm[bn][16 * w * 64]);
      GLL16(kg1 + (size_t)off * DH, &Ksm[bn][16 * w * 64 + 512]);
      GLL16(vg0 + off, &Vsm[bn][16 * w * 64]);
      GLL16(vg1 + off, &Vsm[bn][16 * w * 64 + 512]);
      if (w == 3){
        GLL4(ktg + off, &Ktm[bn][0]);
        asm volatile("s_waitcnt vmcnt(5)" ::: "memory");
      } else {
        asm volatile("s_waitcnt vmcnt(4)" ::: "memory");
      }
    } else {
      asm volatile("s_waitcnt vmcnt(0)" ::: "memory");
    }
    __builtin_amdgcn_s_barrier();

    if (k0 <= qmax){
      // ---- QK^T (swapped): S^T(k,q) ----
      fx16 st[2];
      __builtin_amdgcn_s_setprio(1);
      #pragma unroll
      for (int s = 0; s < 2; ++s){
        const short* kb = &Ksm[buf][(32 * s + l5) * 64];
        fx16 z;
        #pragma unroll
        for (int i = 0; i < 16; ++i) z[i] = 0.f;
        #pragma unroll
        for (int dblk = 0; dblk < 4; ++dblk){
          s16x8 kf = *(const s16x8*)(kb + ((16 * dblk + 8 * hi) ^ ((l5 & 7) << 3)));
          z = mfma32(kf, qf[dblk], z);
        }
        st[s] = z;
      }
      __builtin_amdgcn_s_setprio(0);
      // ---- rank-1 Lorentz time term + causal mask ----
      float p[2][16];
      #pragma unroll
      for (int s = 0; s < 2; ++s)
        #pragma unroll
        for (int m4 = 0; m4 < 4; ++m4){
          fx4 kt4 = *(const fx4*)&Ktm[buf][32 * s + 8 * m4 + 4 * hi];
          #pragma unroll
          for (int tt = 0; tt < 4; ++tt)
            p[s][4 * m4 + tt] = st[s][4 * m4 + tt] + aqt * kt4[tt];
        }
      if (k0 + 63 > q0w){
        #pragma unroll
        for (int s = 0; s < 2; ++s)
          #pragma unroll
          for (int r = 0; r < 16; ++r){
            int kg2 = k0 + 32 * s + (r & 3) + 8 * (r >> 2) + 4 * hi;
            if (kg2 > q) p[s][r] = -3e38f;
          }
      }
      // ---- online softmax: tree max, defer-max (THR=8 in exp2 domain) ----
      float v16[16];
      #pragma unroll
      for (int i = 0; i < 16; ++i) v16[i] = fmaxf(p[0][i], p[1][i]);
      #pragma unroll
      for (int i = 0; i < 8; ++i) v16[i] = fmaxf(v16[i], v16[i + 8]);
      #pragma unroll
      for (int i = 0; i < 4; ++i) v16[i] = fmaxf(v16[i], v16[i + 4]);
      float pmax = fmaxf(fmaxf(v16[0], v16[1]), fmaxf(v16[2], v16[3]));
      pmax = fmaxf(pmax, __shfl_xor(pmax, 32));
      if (!__all(pmax <= mrun + 8.f)){
        float mnew = fmaxf(mrun, pmax);
        float scl = __builtin_amdgcn_exp2f(mrun - mnew);
        mrun = mnew;
        lrun *= scl;
        #pragma unroll
        for (int i = 0; i < 16; ++i){ acc0[i] *= scl; acc1[i] *= scl; }
      }
      float sm[16];
      #pragma unroll
      for (int i = 0; i < 16; ++i){
        p[0][i] = __builtin_amdgcn_exp2f(p[0][i] - mrun);
        p[1][i] = __builtin_amdgcn_exp2f(p[1][i] - mrun);
        sm[i] = p[0][i] + p[1][i];
      }
      #pragma unroll
      for (int i = 0; i < 8; ++i) sm[i] += sm[i + 8];
      #pragma unroll
      for (int i = 0; i < 4; ++i) sm[i] += sm[i + 4];
      float rsum = (sm[0] + sm[1]) + (sm[2] + sm[3]);
      rsum += __shfl_xor(rsum, 32);
      lrun += rsum;

      // ---- pack P to bf16 B-fragments + PV (O^T accumulation) ----
      #pragma unroll
      for (int h = 0; h < 4; ++h){
        int s = h >> 1, hb = h & 1;
        int w0 = cvtpk(p[s][8 * hb + 0], p[s][8 * hb + 1]);
        int w1 = cvtpk(p[s][8 * hb + 2], p[s][8 * hb + 3]);
        int w2 = cvtpk(p[s][8 * hb + 4], p[s][8 * hb + 5]);
        int w3 = cvtpk(p[s][8 * hb + 6], p[s][8 * hb + 7]);
        int sdA = hi ? w0 : w2;
        int sdB = hi ? w1 : w3;
        int rcA = __shfl_xor(sdA, 32);
        int rcB = __shfl_xor(sdB, 32);
        ix4 fw;
        fw.x = hi ? rcA : w0; fw.y = hi ? rcB : w1;
        fw.z = hi ? w2 : rcA; fw.w = hi ? w3 : rcB;
        s16x8 pf = __builtin_bit_cast(s16x8, fw);
        const short* vb0 = &Vsm[buf][(l5) * 64 + ((16 * h + 8 * hi) ^ ((l5 & 7) << 3))];
        const short* vb1 = vb0 + 32 * 64;
        s16x8 vf0 = *(const s16x8*)vb0;
        s16x8 vf1 = *(const s16x8*)vb1;
        __builtin_amdgcn_s_setprio(1);
        acc0 = mfma32(vf0, pf, acc0);
        acc1 = mfma32(vf1, pf, acc1);
        __builtin_amdgcn_s_setprio(0);
      }
    }
    __builtin_amdgcn_s_barrier();
    buf ^= 1;
  }

  // ---- partial outputs: O^T f32 [64 d][32 q] per wave, m/l per q ----
  int slot = bh * 40 + id;
  if (hi == 0){
    Mpart[(size_t)slot * 128 + 32 * w + l5] = mrun;
    Lpart[(size_t)slot * 128 + 32 * w + l5] = lrun;
  }
  float* Op = Opart + (size_t)slot * 8192 + w * 2048;
  #pragma unroll
  for (int r = 0; r < 16; ++r){
    int d = (r & 3) + 8 * (r >> 2) + 4 * hi;
    Op[d * 32 + l5]        = acc0[r];
    Op[(d + 32) * 32 + l5] = acc1[r];
  }
}

// ---- K4b: combine partials -> Obf bf16 ----
__global__ __launch_bounds__(128) void combine_kernel(const float* __restrict__ Mpart,
                                                      const float* __restrict__ Lpart,
                                                      const float* __restrict__ Opart,
                                                      short* __restrict__ Obf){
  int bh = blockIdx.x & 15, g = blockIdx.x >> 4;
  int nch = (g >> 2) + 1;
  int pre = (g < 4) ? g : (g < 8 ? 4 + 2 * (g - 4) : (g < 12 ? 12 + 3 * (g - 8) : 24 + 4 * (g - 12)));
  int base = bh * 40 + pre;
  int qi = threadIdx.x;
  int w = qi >> 5, l = qi & 31;
  float mc[4], wc[4];
  float M = -3e38f;
  #pragma unroll
  for (int c = 0; c < 4; ++c){
    mc[c] = (c < nch) ? Mpart[(size_t)(base + c) * 128 + qi] : -3e38f;
    M = fmaxf(M, mc[c]);
  }
  float L = 0.f;
  #pragma unroll
  for (int c = 0; c < 4; ++c){
    wc[c] = (c < nch) ? __builtin_amdgcn_exp2f(mc[c] - M) : 0.f;
    if (c < nch) L += wc[c] * Lpart[(size_t)(base + c) * 128 + qi];
  }
  float invL = 1.f / L;
  int bb = bh >> 3, hh = bh & 7;
  short* orow = Obf + ((size_t)bb * S_LEN + 128 * g + qi) * DM + hh * DH;
  const float* ob = Opart + (size_t)base * 8192 + w * 2048 + l;
  #pragma unroll
  for (int d8 = 0; d8 < 8; ++d8){
    s16x8 pk;
    #pragma unroll
    for (int dd = 0; dd < 8; ++dd){
      int d = 8 * d8 + dd;
      float o = 0.f;
      #pragma unroll
      for (int c = 0; c < 4; ++c)
        if (c < nch) o += wc[c] * ob[(size_t)c * 8192 + d * 32];
      pk[dd] = f2bf(o * invL);
    }
    *(s16x8*)(orow + 8 * d8) = pk;
  }
}

extern "C" void kernel_launch(void* const* d_in, const int* in_sizes, int n_in,
                              void* d_out, int out_size, void* d_ws, size_t ws_size,
                              hipStream_t stream) {
  const float* x     = (const float*)d_in[0];
  const float* Wq    = (const float*)d_in[1];
  const float* Wk    = (const float*)d_in[2];
  const float* Wv    = (const float*)d_in[3];
  const float* Wo    = (const float*)d_in[4];
  const float* labsK = (const float*)d_in[5];

  char* w = (char*)d_ws;
  short* Wt  = (short*)(w);                                  // 2 MB
  short* xeu = (short*)(w + (2ull  << 20));                  // 4 MB
  float* QKV = (float*)(w + (6ull  << 20));                  // 24 MB (freed after expmap/vtrans)
  float* Opart = (float*)(w + (6ull  << 20));                // 20 MB (reuses QKV region)
  float* Mpart = (float*)(w + (26ull << 20));                // 320 KB
  float* Lpart = (float*)(w + (27ull << 20));                // 320 KB
  short* Qs  = (short*)(w + (30ull << 20));                  // 4 MB
  short* Ks  = (short*)(w + (34ull << 20));                  // 4 MB
  short* Vt  = (short*)(w + (38ull << 20));                  // 4 MB
  float* Qt  = (float*)(w + (42ull << 20));                  // 128 KB
  float* Kt  = (float*)(w + (42ull << 20) + (128ull << 10)); // 128 KB
  short* Obf = (short*)(w + (42ull << 20) + (256ull << 10)); // 4 MB

  const int WTE = DM * DM;
  wt_kernel<<<dim3(8, 8), 256, 0, stream>>>(Wq, Wt + 0 * WTE);
  wt_kernel<<<dim3(8, 8), 256, 0, stream>>>(Wk, Wt + 1 * WTE);
  wt_kernel<<<dim3(8, 8), 256, 0, stream>>>(Wv, Wt + 2 * WTE);
  wt_kernel<<<dim3(8, 8), 256, 0, stream>>>(Wo, Wt + 3 * WTE);

  logmap_kernel<<<MROWS, 128, 0, stream>>>(x, xeu);

  gemm_kernel<<<dim3(8, 32, 3), 256, 0, stream>>>(xeu, Wt, QKV);

  expmap_kernel<<<(B_SZ * S_LEN * NH) / 4, 256, 0, stream>>>(
      QKV, QKV + (size_t)MROWS * DM, labsK, Qt, Qs, Kt, Ks);

  vtrans_kernel<<<dim3(S_LEN / 64, B_SZ * NH), 256, 0, stream>>>(
      QKV + 2ull * MROWS * DM, Vt);

  attn_kernel<<<dim3(640), 256, 0, stream>>>(Qs, Qt, Ks, Kt, Vt, Mpart, Lpart, Opart);

  combine_kernel<<<dim3(256), 128, 0, stream>>>(Mpart, Lpart, Opart, Obf);

  gemm_kernel<<<dim3(8, 32, 1), 256, 0, stream>>>(Obf, Wt + 3 * WTE, (float*)d_out);
}

// Round 4
// 83.818 us; speedup vs baseline: 1.9585x; 1.9585x over previous
//
#include <hip/hip_runtime.h>
#include <math.h>

#define S_LEN 2048
#define B_SZ 2
#define NH 8
#define DH 64
#define DM 512
#define MROWS 4096  // B*S

typedef __attribute__((ext_vector_type(8))) short s16x8;
typedef __attribute__((ext_vector_type(4))) float fx4;
typedef __attribute__((ext_vector_type(16))) float fx16;
typedef __attribute__((ext_vector_type(4))) int ix4;

__device__ inline short f2bf(float x){
  unsigned u = __float_as_uint(x);
  u = (u + 0x7FFFu + ((u >> 16) & 1u)) >> 16;
  return (short)u;
}

__device__ inline fx4 mfma16(s16x8 a, s16x8 b, fx4 c){
  return __builtin_amdgcn_mfma_f32_16x16x32_bf16(a, b, c, 0, 0, 0);
}
__device__ inline fx16 mfma32(s16x8 a, s16x8 b, fx16 c){
  return __builtin_amdgcn_mfma_f32_32x32x16_bf16(a, b, c, 0, 0, 0);
}
__device__ inline int cvtpk(float a, float b){
  int r; asm("v_cvt_pk_bf16_f32 %0, %1, %2" : "=v"(r) : "v"(a), "v"(b)); return r;
}

#define GLL16(g, l) __builtin_amdgcn_global_load_lds((const __attribute__((address_space(1))) void*)(g), (__attribute__((address_space(3))) void*)(l), 16, 0, 0)
#define GLL4(g, l)  __builtin_amdgcn_global_load_lds((const __attribute__((address_space(1))) void*)(g), (__attribute__((address_space(3))) void*)(l), 4, 0, 0)

// ---- K0: f32 weights (K=512, N=512) -> bf16 transposed (N,K); 4 weights in one launch ----
__global__ __launch_bounds__(256) void wt_kernel(const float* __restrict__ W0,
                                                 const float* __restrict__ W1,
                                                 const float* __restrict__ W2,
                                                 const float* __restrict__ W3,
                                                 short* __restrict__ Wt){
  __shared__ short tile[64][66];
  int z = blockIdx.z;
  const float* W = (z == 0) ? W0 : (z == 1) ? W1 : (z == 2) ? W2 : W3;
  short* Wtz = Wt + (size_t)z * DM * DM;
  int n0 = blockIdx.x * 64, k0 = blockIdx.y * 64;
  int t = threadIdx.x;
  int nl = t & 63;
  #pragma unroll
  for (int p = 0; p < 16; ++p){
    int kl = (t >> 6) + p * 4;
    tile[kl][nl] = f2bf(W[(size_t)(k0 + kl) * DM + n0 + nl]);
  }
  __syncthreads();
  int kl2 = t & 63;
  #pragma unroll
  for (int p = 0; p < 16; ++p){
    int nl2 = (t >> 6) + p * 4;
    Wtz[(size_t)(n0 + nl2) * DM + k0 + kl2] = tile[kl2][nl2];
  }
}

// ---- K1: Lorentz log map at origin (K=-1) ----
__global__ __launch_bounds__(128) void logmap_kernel(const float* __restrict__ x,
                                                     short* __restrict__ xeu){
  int row = blockIdx.x;
  const float* xr = x + (size_t)row * (DM + 1);
  int t = threadIdx.x;
  float v[4]; float ss = 0.f;
  #pragma unroll
  for (int j = 0; j < 4; ++j){
    v[j] = xr[1 + t + 128 * j];
    ss += v[j] * v[j];
  }
  #pragma unroll
  for (int off = 1; off < 64; off <<= 1) ss += __shfl_xor(ss, off);
  __shared__ float s2[2];
  if ((t & 63) == 0) s2[t >> 6] = ss;
  __syncthreads();
  float tot = s2[0] + s2[1];
  float nrm = sqrtf(tot);
  float xt = xr[0];
  float theta = acoshf(fmaxf(xt, 1.0f + 1e-7f));
  float scl = theta / fmaxf(nrm, 1e-7f);
  #pragma unroll
  for (int j = 0; j < 4; ++j)
    xeu[(size_t)row * DM + t + 128 * j] = f2bf(scl * v[j]);
}

// ---- K2/K5: LDS-staged GEMM  C(M,512) f32 = A(M,512)bf16 @ Bt(512n,512k)^T ----
__global__ __launch_bounds__(256, 3) void gemm_kernel(const short* __restrict__ A,
                                                      const short* __restrict__ Bt,
                                                      float* __restrict__ C){
  __shared__ __attribute__((aligned(16))) short Asm[2][128 * 64];
  __shared__ __attribute__((aligned(16))) short Bsm[2][64 * 64];
  const int K = DM;
  int z = blockIdx.z;
  Bt += (size_t)z * K * DM;
  C  += (size_t)z * (size_t)MROWS * DM;
  int n0 = blockIdx.x * 64, m0 = blockIdx.y * 128;
  int t = threadIdx.x;
  int w = t >> 6, lane = t & 63;
  int wm = w >> 1, wn = w & 1;
  int lg = lane >> 4, lr = lane & 15;

  int aoff[4]; const short* asrcp[4];
  int boff[2]; const short* bsrcp[2];
  #pragma unroll
  for (int j = 0; j < 4; ++j){
    int ch = t + 256 * j;
    int r = ch >> 3, c = ch & 7;
    aoff[j] = ch * 8;
    asrcp[j] = A + (size_t)(m0 + r) * K + 8 * (c ^ (r & 7));
  }
  #pragma unroll
  for (int j = 0; j < 2; ++j){
    int ch = t + 256 * j;
    int r = ch >> 3, c = ch & 7;
    boff[j] = ch * 8;
    bsrcp[j] = Bt + (size_t)(n0 + r) * K + 8 * (c ^ (r & 7));
  }

  {
    short* ab = &Asm[0][0]; short* bb = &Bsm[0][0];
    #pragma unroll
    for (int j = 0; j < 4; ++j) GLL16(asrcp[j], ab + aoff[j]);
    #pragma unroll
    for (int j = 0; j < 2; ++j) GLL16(bsrcp[j], bb + boff[j]);
  }

  fx4 acc[4][2] = {};
  int buf = 0;
  for (int ks = 0; ks < 8; ++ks){
    if (ks < 7){
      int nb = buf ^ 1;
      short* ab = &Asm[nb][0]; short* bb = &Bsm[nb][0];
      int kk = (ks + 1) * 64;
      #pragma unroll
      for (int j = 0; j < 4; ++j) GLL16(asrcp[j] + kk, ab + aoff[j]);
      #pragma unroll
      for (int j = 0; j < 2; ++j) GLL16(bsrcp[j] + kk, bb + boff[j]);
      asm volatile("s_waitcnt vmcnt(6)" ::: "memory");
    } else {
      asm volatile("s_waitcnt vmcnt(0)" ::: "memory");
    }
    __builtin_amdgcn_s_barrier();

    s16x8 af[4][2], bf[2][2];
    #pragma unroll
    for (int mi = 0; mi < 4; ++mi){
      int row = wm * 64 + mi * 16 + lr;
      #pragma unroll
      for (int s = 0; s < 2; ++s)
        af[mi][s] = *(const s16x8*)&Asm[buf][row * 64 + ((4 * s + lg) ^ (row & 7)) * 8];
    }
    #pragma unroll
    for (int ni = 0; ni < 2; ++ni){
      int row = wn * 32 + ni * 16 + lr;
      #pragma unroll
      for (int s = 0; s < 2; ++s)
        bf[ni][s] = *(const s16x8*)&Bsm[buf][row * 64 + ((4 * s + lg) ^ (row & 7)) * 8];
    }
    #pragma unroll
    for (int s = 0; s < 2; ++s)
      #pragma unroll
      for (int mi = 0; mi < 4; ++mi)
        #pragma unroll
        for (int ni = 0; ni < 2; ++ni)
          acc[mi][ni] = mfma16(af[mi][s], bf[ni][s], acc[mi][ni]);
    __builtin_amdgcn_s_barrier();
    buf ^= 1;
  }

  #pragma unroll
  for (int mi = 0; mi < 4; ++mi)
    #pragma unroll
    for (int ni = 0; ni < 2; ++ni)
      #pragma unroll
      for (int r = 0; r < 4; ++r){
        int row = m0 + wm * 64 + mi * 16 + 4 * lg + r;
        int col = n0 + wn * 32 + ni * 16 + lr;
        C[(size_t)row * DM + col] = acc[mi][ni][r];
      }
}

// ---- K3: per-head exp map + score folding (log2e folded into a) ----
__global__ __launch_bounds__(256) void expmap_kernel(const float* __restrict__ Q,
                                                     const float* __restrict__ Kp,
                                                     const float* __restrict__ labsK,
                                                     float* __restrict__ Qt,
                                                     short* __restrict__ Qs,
                                                     float* __restrict__ Kt,
                                                     short* __restrict__ Ks){
  int idx = blockIdx.x * 4 + (threadIdx.x >> 6);   // (b*S+s)*H + h
  int d = threadIdx.x & 63;
  int h = idx & (NH - 1);
  int bs = idx >> 3;
  int s = bs & (S_LEN - 1);
  int b = bs >> 11;
  float c  = __expf(labsK[h]);
  float sc = sqrtf(c);
  float a  = 0.125f * c * 1.4426950408889634f;
  size_t bhs = ((size_t)(b * NH + h) * S_LEN + s);

  float qv = Q[(size_t)idx * DH + d];
  float ssq = qv * qv;
  #pragma unroll
  for (int off = 1; off < 64; off <<= 1) ssq += __shfl_xor(ssq, off);
  float nq = fmaxf(sqrtf(ssq), 1e-7f);
  float argq = sc * nq;
  float eq = __expf(argq), eqi = __frcp_rn(eq);
  if (d == 0) Qt[bhs] = a * 0.5f * (eq + eqi) / sc;
  float qscale = -a * 0.5f * (eq - eqi) / argq;
  Qs[bhs * DH + d] = f2bf(qscale * qv);

  float kv = Kp[(size_t)idx * DH + d];
  float ksq = kv * kv;
  #pragma unroll
  for (int off = 1; off < 64; off <<= 1) ksq += __shfl_xor(ksq, off);
  float nk = fmaxf(sqrtf(ksq), 1e-7f);
  float argk = sc * nk;
  float ek = __expf(argk), eki = __frcp_rn(ek);
  if (d == 0) Kt[bhs] = 0.5f * (ek + eki) / sc;
  float kscale = 0.5f * (ek - eki) / argk;
  Ks[bhs * DH + d] = f2bf(kscale * kv);
}

// ---- K3b: V (b,s,h,d) f32 -> Vt (b,h,d,s) bf16 ----
__global__ __launch_bounds__(256) void vtrans_kernel(const float* __restrict__ V,
                                                     short* __restrict__ Vt){
  __shared__ short tile[64][66];
  int s0 = blockIdx.x * 64;
  int bh = blockIdx.y;
  int b = bh >> 3, h = bh & 7;
  int t = threadIdx.x;
  int dl = t & 63;
  #pragma unroll
  for (int p = 0; p < 16; ++p){
    int sl = (t >> 6) + p * 4;
    tile[sl][dl] = f2bf(V[((size_t)b * S_LEN + s0 + sl) * DM + h * DH + dl]);
  }
  __syncthreads();
  int sl2 = t & 63;
  #pragma unroll
  for (int p = 0; p < 16; ++p){
    int dl2 = (t >> 6) + p * 4;
    Vt[((size_t)bh * DH + dl2) * S_LEN + s0 + sl2] = tile[sl2][dl2];
  }
}

// ---- K4: flash attention, key-split chunks; emits per-chunk partials ----
__global__ __launch_bounds__(256, 4) void attn_kernel(const short* __restrict__ Qs,
                                                      const float* __restrict__ Qt,
                                                      const short* __restrict__ Ks,
                                                      const float* __restrict__ Kt,
                                                      const short* __restrict__ Vt,
                                                      float* __restrict__ Mpart,
                                                      float* __restrict__ Lpart,
                                                      float* __restrict__ Opart){
  __shared__ __attribute__((aligned(16))) short Ksm[2][4096];
  __shared__ __attribute__((aligned(16))) short Vsm[2][4096];
  __shared__ __attribute__((aligned(16))) float Ktm[2][64];

  int bx = blockIdx.x;
  int bh = bx & 15;
  int id = bx >> 4;                 // 0..39
  int g, c;
  if (id < 4)       { g = id;                 c = 0; }
  else if (id < 12) { g = 4 + ((id - 4) >> 1);  c = (id - 4) & 1; }
  else if (id < 24) { int r = id - 12; int q3 = r / 3; g = 8 + q3; c = r - 3 * q3; }
  else              { g = 12 + ((id - 24) >> 2); c = (id - 24) & 3; }
  int kbeg = 512 * c;
  int kend = 512 * c + 512; { int ge = 128 * g + 128; if (ge < kend) kend = ge; }
  int ntc = (kend - kbeg) >> 6;

  int tid = threadIdx.x;
  int w = tid >> 6, lane = tid & 63;
  int l5 = lane & 31, hi = lane >> 5;
  size_t bhS = (size_t)bh * S_LEN;

  const short* Kg  = Ks + bhS * DH;
  const short* Vg  = Vt + (size_t)bh * DH * S_LEN;
  const float* Ktg = Kt + bhS;

  int srow = lane >> 3;
  int scol = ((lane & 7) * 8) ^ (srow << 3);
  const short* kg0 = Kg + (size_t)(kbeg + 16 * w + srow) * DH + scol;
  const short* kg1 = kg0 + 8 * DH;
  const short* vg0 = Vg + (size_t)(16 * w + srow) * S_LEN + kbeg + scol;
  const short* vg1 = vg0 + 8 * S_LEN;
  const float* ktg = Ktg + kbeg + lane;
  short* Kd0 = &Ksm[0][16 * w * 64]; short* Kd1 = Kd0 + 512;
  short* Vd0 = &Vsm[0][16 * w * 64]; short* Vd1 = Vd0 + 512;

  int q0w = 128 * g + 32 * w;
  int q   = q0w + l5;
  int qmax = q0w + 31;
  s16x8 qf[4];
  #pragma unroll
  for (int dblk = 0; dblk < 4; ++dblk)
    qf[dblk] = *(const s16x8*)(Qs + (bhS + q) * DH + dblk * 16 + hi * 8);
  float aqt = Qt[bhS + q];

  fx16 acc0, acc1;
  #pragma unroll
  for (int i = 0; i < 16; ++i){ acc0[i] = 0.f; acc1[i] = 0.f; }
  float mrun = 0.f, lrun = 0.f;

  GLL16(kg0, Kd0); GLL16(kg1, Kd1);
  GLL16(vg0, Vd0); GLL16(vg1, Vd1);
  if (w == 3) GLL4(ktg, &Ktm[0][0]);
  int buf = 0;

  for (int t = 0; t < ntc; ++t){
    int k0 = kbeg + t * 64;
    if (t + 1 < ntc){
      int off = (t + 1) * 64;
      int bn = buf ^ 1;
      GLL16(kg0 + (size_t)off * DH, &Ksm[bn][16 * w * 64]);
      GLL16(kg1 + (size_t)off * DH, &Ksm[bn][16 * w * 64 + 512]);
      GLL16(vg0 + off, &Vsm[bn][16 * w * 64]);
      GLL16(vg1 + off, &Vsm[bn][16 * w * 64 + 512]);
      if (w == 3){
        GLL4(ktg + off, &Ktm[bn][0]);
        asm volatile("s_waitcnt vmcnt(5)" ::: "memory");
      } else {
        asm volatile("s_waitcnt vmcnt(4)" ::: "memory");
      }
    } else {
      asm volatile("s_waitcnt vmcnt(0)" ::: "memory");
    }
    __builtin_amdgcn_s_barrier();

    if (k0 <= qmax){
      fx16 st[2];
      __builtin_amdgcn_s_setprio(1);
      #pragma unroll
      for (int s = 0; s < 2; ++s){
        const short* kb = &Ksm[buf][(32 * s + l5) * 64];
        fx16 z;
        #pragma unroll
        for (int i = 0; i < 16; ++i) z[i] = 0.f;
        #pragma unroll
        for (int dblk = 0; dblk < 4; ++dblk){
          s16x8 kf = *(const s16x8*)(kb + ((16 * dblk + 8 * hi) ^ ((l5 & 7) << 3)));
          z = mfma32(kf, qf[dblk], z);
        }
        st[s] = z;
      }
      __builtin_amdgcn_s_setprio(0);
      float p[2][16];
      #pragma unroll
      for (int s = 0; s < 2; ++s)
        #pragma unroll
        for (int m4 = 0; m4 < 4; ++m4){
          fx4 kt4 = *(const fx4*)&Ktm[buf][32 * s + 8 * m4 + 4 * hi];
          #pragma unroll
          for (int tt = 0; tt < 4; ++tt)
            p[s][4 * m4 + tt] = st[s][4 * m4 + tt] + aqt * kt4[tt];
        }
      if (k0 + 63 > q0w){
        #pragma unroll
        for (int s = 0; s < 2; ++s)
          #pragma unroll
          for (int r = 0; r < 16; ++r){
            int kg2 = k0 + 32 * s + (r & 3) + 8 * (r >> 2) + 4 * hi;
            if (kg2 > q) p[s][r] = -3e38f;
          }
      }
      float v16[16];
      #pragma unroll
      for (int i = 0; i < 16; ++i) v16[i] = fmaxf(p[0][i], p[1][i]);
      #pragma unroll
      for (int i = 0; i < 8; ++i) v16[i] = fmaxf(v16[i], v16[i + 8]);
      #pragma unroll
      for (int i = 0; i < 4; ++i) v16[i] = fmaxf(v16[i], v16[i + 4]);
      float pmax = fmaxf(fmaxf(v16[0], v16[1]), fmaxf(v16[2], v16[3]));
      pmax = fmaxf(pmax, __shfl_xor(pmax, 32));
      if (!__all(pmax <= mrun + 8.f)){
        float mnew = fmaxf(mrun, pmax);
        float scl = __builtin_amdgcn_exp2f(mrun - mnew);
        mrun = mnew;
        lrun *= scl;
        #pragma unroll
        for (int i = 0; i < 16; ++i){ acc0[i] *= scl; acc1[i] *= scl; }
      }
      float sm[16];
      #pragma unroll
      for (int i = 0; i < 16; ++i){
        p[0][i] = __builtin_amdgcn_exp2f(p[0][i] - mrun);
        p[1][i] = __builtin_amdgcn_exp2f(p[1][i] - mrun);
        sm[i] = p[0][i] + p[1][i];
      }
      #pragma unroll
      for (int i = 0; i < 8; ++i) sm[i] += sm[i + 8];
      #pragma unroll
      for (int i = 0; i < 4; ++i) sm[i] += sm[i + 4];
      float rsum = (sm[0] + sm[1]) + (sm[2] + sm[3]);
      rsum += __shfl_xor(rsum, 32);
      lrun += rsum;

      #pragma unroll
      for (int h = 0; h < 4; ++h){
        int s = h >> 1, hb = h & 1;
        int w0 = cvtpk(p[s][8 * hb + 0], p[s][8 * hb + 1]);
        int w1 = cvtpk(p[s][8 * hb + 2], p[s][8 * hb + 3]);
        int w2 = cvtpk(p[s][8 * hb + 4], p[s][8 * hb + 5]);
        int w3 = cvtpk(p[s][8 * hb + 6], p[s][8 * hb + 7]);
        int sdA = hi ? w0 : w2;
        int sdB = hi ? w1 : w3;
        int rcA = __shfl_xor(sdA, 32);
        int rcB = __shfl_xor(sdB, 32);
        ix4 fw;
        fw.x = hi ? rcA : w0; fw.y = hi ? rcB : w1;
        fw.z = hi ? w2 : rcA; fw.w = hi ? w3 : rcB;
        s16x8 pf = __builtin_bit_cast(s16x8, fw);
        const short* vb0 = &Vsm[buf][(l5) * 64 + ((16 * h + 8 * hi) ^ ((l5 & 7) << 3))];
        const short* vb1 = vb0 + 32 * 64;
        s16x8 vf0 = *(const s16x8*)vb0;
        s16x8 vf1 = *(const s16x8*)vb1;
        __builtin_amdgcn_s_setprio(1);
        acc0 = mfma32(vf0, pf, acc0);
        acc1 = mfma32(vf1, pf, acc1);
        __builtin_amdgcn_s_setprio(0);
      }
    }
    __builtin_amdgcn_s_barrier();
    buf ^= 1;
  }

  int slot = bh * 40 + id;
  if (hi == 0){
    Mpart[(size_t)slot * 128 + 32 * w + l5] = mrun;
    Lpart[(size_t)slot * 128 + 32 * w + l5] = lrun;
  }
  float* Op = Opart + (size_t)slot * 8192 + w * 2048;
  #pragma unroll
  for (int r = 0; r < 16; ++r){
    int d = (r & 3) + 8 * (r >> 2) + 4 * hi;
    Op[d * 32 + l5]        = acc0[r];
    Op[(d + 32) * 32 + l5] = acc1[r];
  }
}

// ---- K4b: combine partials -> Obf bf16. 1024 blocks x 256 thr, branchless weights ----
__global__ __launch_bounds__(256) void combine_kernel(const float* __restrict__ Mpart,
                                                      const float* __restrict__ Lpart,
                                                      const float* __restrict__ Opart,
                                                      short* __restrict__ Obf){
  int bx = blockIdx.x;
  int bhg = bx & 255;
  int bh = bhg & 15, g = bhg >> 4;
  int t = threadIdx.x;
  int q = t & 127;
  int dquad = (t >> 7) | ((bx >> 8) << 1);   // 0..7
  int nch = (g >> 2) + 1;
  int pre = (g < 4) ? g : (g < 8 ? 4 + 2 * (g - 4) : (g < 12 ? 12 + 3 * (g - 8) : 24 + 4 * (g - 12)));
  int base = bh * 40 + pre;
  int w = q >> 5, l = q & 31;

  float mc[4], lc[4];
  #pragma unroll
  for (int c = 0; c < 4; ++c){
    mc[c] = Mpart[(size_t)(base + c) * 128 + q];
    lc[c] = Lpart[(size_t)(base + c) * 128 + q];
    if (c >= nch) mc[c] = -3e38f;       // uniform scalar branch; exp2 -> weight 0
  }
  float M = fmaxf(fmaxf(mc[0], mc[1]), fmaxf(mc[2], mc[3]));
  float wc[4]; float L = 0.f;
  #pragma unroll
  for (int c = 0; c < 4; ++c){
    wc[c] = __builtin_amdgcn_exp2f(mc[c] - M);
    L += wc[c] * lc[c];
  }
  float invL = 1.f / L;
  #pragma unroll
  for (int c = 0; c < 4; ++c) wc[c] *= invL;

  const float* ob = Opart + (size_t)base * 8192 + w * 2048 + dquad * 256 + l;
  float f[4][8];
  #pragma unroll
  for (int c = 0; c < 4; ++c)
    #pragma unroll
    for (int dd = 0; dd < 8; ++dd)
      f[c][dd] = ob[(size_t)c * 8192 + dd * 32];
  s16x8 pk;
  #pragma unroll
  for (int dd = 0; dd < 8; ++dd){
    float o = wc[0] * f[0][dd] + wc[1] * f[1][dd] + wc[2] * f[2][dd] + wc[3] * f[3][dd];
    pk[dd] = f2bf(o);
  }
  int bb = bh >> 3, hh = bh & 7;
  *(s16x8*)(Obf + ((size_t)bb * S_LEN + 128 * g + q) * DM + hh * DH + dquad * 8) = pk;
}

extern "C" void kernel_launch(void* const* d_in, const int* in_sizes, int n_in,
                              void* d_out, int out_size, void* d_ws, size_t ws_size,
                              hipStream_t stream) {
  const float* x     = (const float*)d_in[0];
  const float* Wq    = (const float*)d_in[1];
  const float* Wk    = (const float*)d_in[2];
  const float* Wv    = (const float*)d_in[3];
  const float* Wo    = (const float*)d_in[4];
  const float* labsK = (const float*)d_in[5];

  char* w = (char*)d_ws;
  short* Wt  = (short*)(w);                                  // 2 MB
  short* xeu = (short*)(w + (2ull  << 20));                  // 4 MB
  float* QKV = (float*)(w + (6ull  << 20));                  // 24 MB
  float* Opart = (float*)(w + (6ull  << 20));                // 20 MB (reuses QKV region)
  float* Mpart = (float*)(w + (26ull << 20));                // 320 KB
  float* Lpart = (float*)(w + (27ull << 20));                // 320 KB
  short* Qs  = (short*)(w + (30ull << 20));                  // 4 MB
  short* Ks  = (short*)(w + (34ull << 20));                  // 4 MB
  short* Vt  = (short*)(w + (38ull << 20));                  // 4 MB
  float* Qt  = (float*)(w + (42ull << 20));                  // 128 KB
  float* Kt  = (float*)(w + (42ull << 20) + (128ull << 10)); // 128 KB
  short* Obf = (short*)(w + (42ull << 20) + (256ull << 10)); // 4 MB

  wt_kernel<<<dim3(8, 8, 4), 256, 0, stream>>>(Wq, Wk, Wv, Wo, Wt);

  logmap_kernel<<<MROWS, 128, 0, stream>>>(x, xeu);

  gemm_kernel<<<dim3(8, 32, 3), 256, 0, stream>>>(xeu, Wt, QKV);

  expmap_kernel<<<(B_SZ * S_LEN * NH) / 4, 256, 0, stream>>>(
      QKV, QKV + (size_t)MROWS * DM, labsK, Qt, Qs, Kt, Ks);

  vtrans_kernel<<<dim3(S_LEN / 64, B_SZ * NH), 256, 0, stream>>>(
      QKV + 2ull * MROWS * DM, Vt);

  attn_kernel<<<dim3(640), 256, 0, stream>>>(Qs, Qt, Ks, Kt, Vt, Mpart, Lpart, Opart);

  combine_kernel<<<dim3(1024), 256, 0, stream>>>(Mpart, Lpart, Opart, Obf);

  gemm_kernel<<<dim3(8, 32, 1), 256, 0, stream>>>(Obf, Wt + 3 * DM * DM, (float*)d_out);
}

// Round 5
// 66.284 us; speedup vs baseline: 2.4766x; 1.2645x over previous
//
#include <hip/hip_runtime.h>
#include <math.h>

#define S_LEN 2048
#define B_SZ 2
#define NH 8
#define DH 64
#define DM 512
#define MROWS 4096  // B*S

typedef __attribute__((ext_vector_type(8))) short s16x8;
typedef __attribute__((ext_vector_type(4))) float fx4;
typedef __attribute__((ext_vector_type(16))) float fx16;
typedef __attribute__((ext_vector_type(4))) int ix4;

__device__ inline short f2bf(float x){
  unsigned u = __float_as_uint(x);
  u = (u + 0x7FFFu + ((u >> 16) & 1u)) >> 16;
  return (short)u;
}

__device__ inline fx4 mfma16(s16x8 a, s16x8 b, fx4 c){
  return __builtin_amdgcn_mfma_f32_16x16x32_bf16(a, b, c, 0, 0, 0);
}
__device__ inline fx16 mfma32(s16x8 a, s16x8 b, fx16 c){
  return __builtin_amdgcn_mfma_f32_32x32x16_bf16(a, b, c, 0, 0, 0);
}
__device__ inline int cvtpk(float a, float b){
  int r; asm("v_cvt_pk_bf16_f32 %0, %1, %2" : "=v"(r) : "v"(a), "v"(b)); return r;
}

#define GLL16(g, l) __builtin_amdgcn_global_load_lds((const __attribute__((address_space(1))) void*)(g), (__attribute__((address_space(3))) void*)(l), 16, 0, 0)
#define GLL4(g, l)  __builtin_amdgcn_global_load_lds((const __attribute__((address_space(1))) void*)(g), (__attribute__((address_space(3))) void*)(l), 4, 0, 0)

// ---- K0: fused weight-transpose (blocks 0..255) + logmap (blocks 256..2303) ----
__global__ __launch_bounds__(256) void prep_kernel(const float* __restrict__ W0,
                                                   const float* __restrict__ W1,
                                                   const float* __restrict__ W2,
                                                   const float* __restrict__ W3,
                                                   short* __restrict__ Wt,
                                                   const float* __restrict__ x,
                                                   short* __restrict__ xeu){
  __shared__ short tile[64][66];
  __shared__ float s4[4];
  int bid = blockIdx.x;
  int t = threadIdx.x;
  if (bid < 256){
    int z = bid >> 6, rem = bid & 63;
    const float* W = (z == 0) ? W0 : (z == 1) ? W1 : (z == 2) ? W2 : W3;
    short* Wtz = Wt + (size_t)z * DM * DM;
    int n0 = (rem & 7) * 64, k0 = (rem >> 3) * 64;
    int nl = t & 63;
    #pragma unroll
    for (int p = 0; p < 16; ++p){
      int kl = (t >> 6) + p * 4;
      tile[kl][nl] = f2bf(W[(size_t)(k0 + kl) * DM + n0 + nl]);
    }
    __syncthreads();
    int kl2 = t & 63;
    #pragma unroll
    for (int p = 0; p < 16; ++p){
      int nl2 = (t >> 6) + p * 4;
      Wtz[(size_t)(n0 + nl2) * DM + k0 + kl2] = tile[kl2][nl2];
    }
  } else {
    int row = 2 * (bid - 256) + (t >> 7);
    int tl = t & 127;
    const float* xr = x + (size_t)row * (DM + 1);
    float v[4]; float ss = 0.f;
    #pragma unroll
    for (int j = 0; j < 4; ++j){
      v[j] = xr[1 + tl + 128 * j];
      ss += v[j] * v[j];
    }
    #pragma unroll
    for (int off = 1; off < 64; off <<= 1) ss += __shfl_xor(ss, off);
    if ((t & 63) == 0) s4[t >> 6] = ss;
    __syncthreads();
    int g2 = t >> 7;
    float tot = s4[2 * g2] + s4[2 * g2 + 1];
    float nrm = sqrtf(tot);
    float xt = xr[0];
    float theta = acoshf(fmaxf(xt, 1.0f + 1e-7f));
    float scl = theta / fmaxf(nrm, 1e-7f);
    #pragma unroll
    for (int j = 0; j < 4; ++j)
      xeu[(size_t)row * DM + tl + 128 * j] = f2bf(scl * v[j]);
  }
}

// ---- K2: QKV GEMM with fused exp-map / V-transpose epilogue ----
// tile 128m x 64n (n-tile == one head), BK=64, z: 0=Q,1=K,2=V.
__global__ __launch_bounds__(256, 3) void gemm_fused_kernel(const short* __restrict__ A,
                                                            const short* __restrict__ Bt,
                                                            const float* __restrict__ labsK,
                                                            float* __restrict__ Qt,
                                                            short* __restrict__ Qs,
                                                            float* __restrict__ Kt,
                                                            short* __restrict__ Ks,
                                                            short* __restrict__ Vt){
  __shared__ __attribute__((aligned(16))) short Asm[2][128 * 64];
  __shared__ __attribute__((aligned(16))) short Bsm[2][64 * 64];
  __shared__ float nrm2s[2][128];
  const int K = DM;
  int z = blockIdx.z;
  int h = blockIdx.x;                 // head
  int n0 = h * 64, m0 = blockIdx.y * 128;
  int t = threadIdx.x;
  int w = t >> 6, lane = t & 63;
  int wm = w >> 1, wn = w & 1;
  int lg = lane >> 4, lr = lane & 15;
  const short* Btz = Bt + (size_t)z * K * DM;

  int aoff[4]; const short* asrcp[4];
  int boff[2]; const short* bsrcp[2];
  #pragma unroll
  for (int j = 0; j < 4; ++j){
    int ch = t + 256 * j;
    int r = ch >> 3, c = ch & 7;
    aoff[j] = ch * 8;
    asrcp[j] = A + (size_t)(m0 + r) * K + 8 * (c ^ (r & 7));
  }
  #pragma unroll
  for (int j = 0; j < 2; ++j){
    int ch = t + 256 * j;
    int r = ch >> 3, c = ch & 7;
    boff[j] = ch * 8;
    bsrcp[j] = Btz + (size_t)(n0 + r) * K + 8 * (c ^ (r & 7));
  }

  {
    short* ab = &Asm[0][0]; short* bb = &Bsm[0][0];
    #pragma unroll
    for (int j = 0; j < 4; ++j) GLL16(asrcp[j], ab + aoff[j]);
    #pragma unroll
    for (int j = 0; j < 2; ++j) GLL16(bsrcp[j], bb + boff[j]);
  }

  fx4 acc[4][2] = {};
  int buf = 0;
  for (int ks = 0; ks < 8; ++ks){
    if (ks < 7){
      int nb = buf ^ 1;
      short* ab = &Asm[nb][0]; short* bb = &Bsm[nb][0];
      int kk = (ks + 1) * 64;
      #pragma unroll
      for (int j = 0; j < 4; ++j) GLL16(asrcp[j] + kk, ab + aoff[j]);
      #pragma unroll
      for (int j = 0; j < 2; ++j) GLL16(bsrcp[j] + kk, bb + boff[j]);
      asm volatile("s_waitcnt vmcnt(6)" ::: "memory");
    } else {
      asm volatile("s_waitcnt vmcnt(0)" ::: "memory");
    }
    __builtin_amdgcn_s_barrier();

    s16x8 af[4][2], bf[2][2];
    #pragma unroll
    for (int mi = 0; mi < 4; ++mi){
      int row = wm * 64 + mi * 16 + lr;
      #pragma unroll
      for (int s = 0; s < 2; ++s)
        af[mi][s] = *(const s16x8*)&Asm[buf][row * 64 + ((4 * s + lg) ^ (row & 7)) * 8];
    }
    #pragma unroll
    for (int ni = 0; ni < 2; ++ni){
      int row = wn * 32 + ni * 16 + lr;
      #pragma unroll
      for (int s = 0; s < 2; ++s)
        bf[ni][s] = *(const s16x8*)&Bsm[buf][row * 64 + ((4 * s + lg) ^ (row & 7)) * 8];
    }
    #pragma unroll
    for (int s = 0; s < 2; ++s)
      #pragma unroll
      for (int mi = 0; mi < 4; ++mi)
        #pragma unroll
        for (int ni = 0; ni < 2; ++ni)
          acc[mi][ni] = mfma16(af[mi][s], bf[ni][s], acc[mi][ni]);
    __builtin_amdgcn_s_barrier();
    buf ^= 1;
  }

  if (z < 2){
    // ---- fused exp-map epilogue (Q or K) ----
    #pragma unroll
    for (int mi = 0; mi < 4; ++mi)
      #pragma unroll
      for (int r = 0; r < 4; ++r){
        float prt = acc[mi][0][r] * acc[mi][0][r] + acc[mi][1][r] * acc[mi][1][r];
        prt += __shfl_xor(prt, 1);
        prt += __shfl_xor(prt, 2);
        prt += __shfl_xor(prt, 4);
        prt += __shfl_xor(prt, 8);
        if (lr == 0) nrm2s[wn][wm * 64 + mi * 16 + 4 * lg + r] = prt;
      }
    __syncthreads();
    float c  = __expf(labsK[h]);
    float sc = sqrtf(c);
    float invsc = __frcp_rn(sc);
    float a  = 0.125f * c * 1.4426950408889634f;
    float tmul = (z == 0) ? a : 1.0f;
    float vmul = (z == 0) ? -a : 1.0f;
    float* Tt = (z == 0) ? Qt : Kt;
    short* Ts = (z == 0) ? Qs : Ks;
    #pragma unroll
    for (int mi = 0; mi < 4; ++mi)
      #pragma unroll
      for (int r = 0; r < 4; ++r){
        int row_local = wm * 64 + mi * 16 + 4 * lg + r;
        float full = nrm2s[0][row_local] + nrm2s[1][row_local];
        float n = fmaxf(sqrtf(full), 1e-7f);
        float arg = sc * n;
        float e = __expf(arg), ei = __frcp_rn(e);
        float tval = tmul * 0.5f * (e + ei) * invsc;
        float vscl = vmul * 0.5f * (e - ei) * __frcp_rn(arg);
        int grow = m0 + row_local;
        int b = grow >> 11, s = grow & (S_LEN - 1);
        size_t bhs = ((size_t)(b * NH + h) * S_LEN + s);
        if (lr == 0) Tt[bhs] = tval;
        #pragma unroll
        for (int ni = 0; ni < 2; ++ni)
          Ts[bhs * DH + wn * 32 + ni * 16 + lr] = f2bf(vscl * acc[mi][ni][r]);
      }
  } else {
    // ---- fused V transpose epilogue: acc -> LDS [64 d][136 pad] -> Vt (bh,d,s) bf16 ----
    short* vt = (short*)&Asm[0][0];   // 64*136 shorts = 17.4 KB (staging dead now)
    #pragma unroll
    for (int mi = 0; mi < 4; ++mi)
      #pragma unroll
      for (int ni = 0; ni < 2; ++ni)
        #pragma unroll
        for (int r = 0; r < 4; ++r){
          int row_local = wm * 64 + mi * 16 + 4 * lg + r;
          int col_local = wn * 32 + ni * 16 + lr;
          vt[col_local * 136 + row_local] = f2bf(acc[mi][ni][r]);
        }
    __syncthreads();
    int d = t >> 2, sseg = (t & 3) * 32;
    int b = m0 >> 11;
    size_t vbase = ((size_t)(b * NH + h) * DH + d) * S_LEN + (m0 & (S_LEN - 1)) + sseg;
    #pragma unroll
    for (int j = 0; j < 4; ++j){
      s16x8 val = *(const s16x8*)&vt[d * 136 + sseg + 8 * j];
      *(s16x8*)(Vt + vbase + 8 * j) = val;
    }
  }
}

// ---- K4: flash attention, key-split chunks; emits per-chunk partials ----
__global__ __launch_bounds__(256, 4) void attn_kernel(const short* __restrict__ Qs,
                                                      const float* __restrict__ Qt,
                                                      const short* __restrict__ Ks,
                                                      const float* __restrict__ Kt,
                                                      const short* __restrict__ Vt,
                                                      float* __restrict__ Mpart,
                                                      float* __restrict__ Lpart,
                                                      float* __restrict__ Opart){
  __shared__ __attribute__((aligned(16))) short Ksm[2][4096];
  __shared__ __attribute__((aligned(16))) short Vsm[2][4096];
  __shared__ __attribute__((aligned(16))) float Ktm[2][64];

  int bx = blockIdx.x;
  int bh = bx & 15;
  int id = bx >> 4;                 // 0..39
  int g, c;
  if (id < 4)       { g = id;                 c = 0; }
  else if (id < 12) { g = 4 + ((id - 4) >> 1);  c = (id - 4) & 1; }
  else if (id < 24) { int r = id - 12; int q3 = r / 3; g = 8 + q3; c = r - 3 * q3; }
  else              { g = 12 + ((id - 24) >> 2); c = (id - 24) & 3; }
  int kbeg = 512 * c;
  int kend = 512 * c + 512; { int ge = 128 * g + 128; if (ge < kend) kend = ge; }
  int ntc = (kend - kbeg) >> 6;

  int tid = threadIdx.x;
  int w = tid >> 6, lane = tid & 63;
  int l5 = lane & 31, hi = lane >> 5;
  size_t bhS = (size_t)bh * S_LEN;

  const short* Kg  = Ks + bhS * DH;
  const short* Vg  = Vt + (size_t)bh * DH * S_LEN;
  const float* Ktg = Kt + bhS;

  int srow = lane >> 3;
  int scol = ((lane & 7) * 8) ^ (srow << 3);
  const short* kg0 = Kg + (size_t)(kbeg + 16 * w + srow) * DH + scol;
  const short* kg1 = kg0 + 8 * DH;
  const short* vg0 = Vg + (size_t)(16 * w + srow) * S_LEN + kbeg + scol;
  const short* vg1 = vg0 + 8 * S_LEN;
  const float* ktg = Ktg + kbeg + lane;
  short* Kd0 = &Ksm[0][16 * w * 64]; short* Kd1 = Kd0 + 512;
  short* Vd0 = &Vsm[0][16 * w * 64]; short* Vd1 = Vd0 + 512;

  int q0w = 128 * g + 32 * w;
  int q   = q0w + l5;
  int qmax = q0w + 31;
  s16x8 qf[4];
  #pragma unroll
  for (int dblk = 0; dblk < 4; ++dblk)
    qf[dblk] = *(const s16x8*)(Qs + (bhS + q) * DH + dblk * 16 + hi * 8);
  float aqt = Qt[bhS + q];

  fx16 acc0, acc1;
  #pragma unroll
  for (int i = 0; i < 16; ++i){ acc0[i] = 0.f; acc1[i] = 0.f; }
  float mrun = 0.f, lrun = 0.f;

  GLL16(kg0, Kd0); GLL16(kg1, Kd1);
  GLL16(vg0, Vd0); GLL16(vg1, Vd1);
  if (w == 3) GLL4(ktg, &Ktm[0][0]);
  int buf = 0;

  for (int t = 0; t < ntc; ++t){
    int k0 = kbeg + t * 64;
    if (t + 1 < ntc){
      int off = (t + 1) * 64;
      int bn = buf ^ 1;
      GLL16(kg0 + (size_t)off * DH, &Ksm[bn][16 * w * 64]);
      GLL16(kg1 + (size_t)off * DH, &Ksm[bn][16 * w * 64 + 512]);
      GLL16(vg0 + off, &Vsm[bn][16 * w * 64]);
      GLL16(vg1 + off, &Vsm[bn][16 * w * 64 + 512]);
      if (w == 3){
        GLL4(ktg + off, &Ktm[bn][0]);
        asm volatile("s_waitcnt vmcnt(5)" ::: "memory");
      } else {
        asm volatile("s_waitcnt vmcnt(4)" ::: "memory");
      }
    } else {
      asm volatile("s_waitcnt vmcnt(0)" ::: "memory");
    }
    __builtin_amdgcn_s_barrier();

    if (k0 <= qmax){
      fx16 st[2];
      __builtin_amdgcn_s_setprio(1);
      #pragma unroll
      for (int s = 0; s < 2; ++s){
        const short* kb = &Ksm[buf][(32 * s + l5) * 64];
        fx16 z;
        #pragma unroll
        for (int i = 0; i < 16; ++i) z[i] = 0.f;
        #pragma unroll
        for (int dblk = 0; dblk < 4; ++dblk){
          s16x8 kf = *(const s16x8*)(kb + ((16 * dblk + 8 * hi) ^ ((l5 & 7) << 3)));
          z = mfma32(kf, qf[dblk], z);
        }
        st[s] = z;
      }
      __builtin_amdgcn_s_setprio(0);
      float p[2][16];
      #pragma unroll
      for (int s = 0; s < 2; ++s)
        #pragma unroll
        for (int m4 = 0; m4 < 4; ++m4){
          fx4 kt4 = *(const fx4*)&Ktm[buf][32 * s + 8 * m4 + 4 * hi];
          #pragma unroll
          for (int tt = 0; tt < 4; ++tt)
            p[s][4 * m4 + tt] = st[s][4 * m4 + tt] + aqt * kt4[tt];
        }
      if (k0 + 63 > q0w){
        #pragma unroll
        for (int s = 0; s < 2; ++s)
          #pragma unroll
          for (int r = 0; r < 16; ++r){
            int kg2 = k0 + 32 * s + (r & 3) + 8 * (r >> 2) + 4 * hi;
            if (kg2 > q) p[s][r] = -3e38f;
          }
      }
      float v16[16];
      #pragma unroll
      for (int i = 0; i < 16; ++i) v16[i] = fmaxf(p[0][i], p[1][i]);
      #pragma unroll
      for (int i = 0; i < 8; ++i) v16[i] = fmaxf(v16[i], v16[i + 8]);
      #pragma unroll
      for (int i = 0; i < 4; ++i) v16[i] = fmaxf(v16[i], v16[i + 4]);
      float pmax = fmaxf(fmaxf(v16[0], v16[1]), fmaxf(v16[2], v16[3]));
      pmax = fmaxf(pmax, __shfl_xor(pmax, 32));
      if (!__all(pmax <= mrun + 8.f)){
        float mnew = fmaxf(mrun, pmax);
        float scl = __builtin_amdgcn_exp2f(mrun - mnew);
        mrun = mnew;
        lrun *= scl;
        #pragma unroll
        for (int i = 0; i < 16; ++i){ acc0[i] *= scl; acc1[i] *= scl; }
      }
      float sm[16];
      #pragma unroll
      for (int i = 0; i < 16; ++i){
        p[0][i] = __builtin_amdgcn_exp2f(p[0][i] - mrun);
        p[1][i] = __builtin_amdgcn_exp2f(p[1][i] - mrun);
        sm[i] = p[0][i] + p[1][i];
      }
      #pragma unroll
      for (int i = 0; i < 8; ++i) sm[i] += sm[i + 8];
      #pragma unroll
      for (int i = 0; i < 4; ++i) sm[i] += sm[i + 4];
      float rsum = (sm[0] + sm[1]) + (sm[2] + sm[3]);
      rsum += __shfl_xor(rsum, 32);
      lrun += rsum;

      #pragma unroll
      for (int h = 0; h < 4; ++h){
        int s = h >> 1, hb = h & 1;
        int w0 = cvtpk(p[s][8 * hb + 0], p[s][8 * hb + 1]);
        int w1 = cvtpk(p[s][8 * hb + 2], p[s][8 * hb + 3]);
        int w2 = cvtpk(p[s][8 * hb + 4], p[s][8 * hb + 5]);
        int w3 = cvtpk(p[s][8 * hb + 6], p[s][8 * hb + 7]);
        int sdA = hi ? w0 : w2;
        int sdB = hi ? w1 : w3;
        int rcA = __shfl_xor(sdA, 32);
        int rcB = __shfl_xor(sdB, 32);
        ix4 fw;
        fw.x = hi ? rcA : w0; fw.y = hi ? rcB : w1;
        fw.z = hi ? w2 : rcA; fw.w = hi ? w3 : rcB;
        s16x8 pf = __builtin_bit_cast(s16x8, fw);
        const short* vb0 = &Vsm[buf][(l5) * 64 + ((16 * h + 8 * hi) ^ ((l5 & 7) << 3))];
        const short* vb1 = vb0 + 32 * 64;
        s16x8 vf0 = *(const s16x8*)vb0;
        s16x8 vf1 = *(const s16x8*)vb1;
        __builtin_amdgcn_s_setprio(1);
        acc0 = mfma32(vf0, pf, acc0);
        acc1 = mfma32(vf1, pf, acc1);
        __builtin_amdgcn_s_setprio(0);
      }
    }
    __builtin_amdgcn_s_barrier();
    buf ^= 1;
  }

  int slot = bh * 40 + id;
  if (hi == 0){
    Mpart[(size_t)slot * 128 + 32 * w + l5] = mrun;
    Lpart[(size_t)slot * 128 + 32 * w + l5] = lrun;
  }
  float* Op = Opart + (size_t)slot * 8192 + w * 2048;
  #pragma unroll
  for (int r = 0; r < 16; ++r){
    int d = (r & 3) + 8 * (r >> 2) + 4 * hi;
    Op[d * 32 + l5]        = acc0[r];
    Op[(d + 32) * 32 + l5] = acc1[r];
  }
}

// ---- K4b: combine partials -> Obf bf16 ----
__global__ __launch_bounds__(256) void combine_kernel(const float* __restrict__ Mpart,
                                                      const float* __restrict__ Lpart,
                                                      const float* __restrict__ Opart,
                                                      short* __restrict__ Obf){
  int bx = blockIdx.x;
  int bhg = bx & 255;
  int bh = bhg & 15, g = bhg >> 4;
  int t = threadIdx.x;
  int q = t & 127;
  int dquad = (t >> 7) | ((bx >> 8) << 1);   // 0..7
  int nch = (g >> 2) + 1;
  int pre = (g < 4) ? g : (g < 8 ? 4 + 2 * (g - 4) : (g < 12 ? 12 + 3 * (g - 8) : 24 + 4 * (g - 12)));
  int base = bh * 40 + pre;
  int w = q >> 5, l = q & 31;

  float mc[4], lc[4];
  #pragma unroll
  for (int c = 0; c < 4; ++c){
    mc[c] = Mpart[(size_t)(base + c) * 128 + q];
    lc[c] = Lpart[(size_t)(base + c) * 128 + q];
    if (c >= nch) mc[c] = -3e38f;
  }
  float M = fmaxf(fmaxf(mc[0], mc[1]), fmaxf(mc[2], mc[3]));
  float wc[4]; float L = 0.f;
  #pragma unroll
  for (int c = 0; c < 4; ++c){
    wc[c] = __builtin_amdgcn_exp2f(mc[c] - M);
    L += wc[c] * lc[c];
  }
  float invL = 1.f / L;
  #pragma unroll
  for (int c = 0; c < 4; ++c) wc[c] *= invL;

  const float* ob = Opart + (size_t)base * 8192 + w * 2048 + dquad * 256 + l;
  float f[4][8];
  #pragma unroll
  for (int c = 0; c < 4; ++c)
    #pragma unroll
    for (int dd = 0; dd < 8; ++dd)
      f[c][dd] = ob[(size_t)c * 8192 + dd * 32];
  s16x8 pk;
  #pragma unroll
  for (int dd = 0; dd < 8; ++dd){
    float o = wc[0] * f[0][dd] + wc[1] * f[1][dd] + wc[2] * f[2][dd] + wc[3] * f[3][dd];
    pk[dd] = f2bf(o);
  }
  int bb = bh >> 3, hh = bh & 7;
  *(s16x8*)(Obf + ((size_t)bb * S_LEN + 128 * g + q) * DM + hh * DH + dquad * 8) = pk;
}

// ---- K5: O-projection GEMM, 64x64 tiles (512 blocks -> 2/CU) ----
__global__ __launch_bounds__(256, 4) void gemm_o_kernel(const short* __restrict__ A,
                                                        const short* __restrict__ Bt,
                                                        float* __restrict__ C){
  __shared__ __attribute__((aligned(16))) short Asm[2][64 * 64];
  __shared__ __attribute__((aligned(16))) short Bsm[2][64 * 64];
  const int K = DM;
  int n0 = blockIdx.x * 64, m0 = blockIdx.y * 64;
  int t = threadIdx.x;
  int w = t >> 6, lane = t & 63;
  int wm = w >> 1, wn = w & 1;
  int lg = lane >> 4, lr = lane & 15;

  int aoff[2]; const short* asrcp[2];
  int boff[2]; const short* bsrcp[2];
  #pragma unroll
  for (int j = 0; j < 2; ++j){
    int ch = t + 256 * j;
    int r = ch >> 3, c = ch & 7;
    aoff[j] = ch * 8;
    asrcp[j] = A + (size_t)(m0 + r) * K + 8 * (c ^ (r & 7));
    boff[j] = ch * 8;
    bsrcp[j] = Bt + (size_t)(n0 + r) * K + 8 * (c ^ (r & 7));
  }

  {
    short* ab = &Asm[0][0]; short* bb = &Bsm[0][0];
    #pragma unroll
    for (int j = 0; j < 2; ++j){ GLL16(asrcp[j], ab + aoff[j]); GLL16(bsrcp[j], bb + boff[j]); }
  }

  fx4 acc[2][2] = {};
  int buf = 0;
  for (int ks = 0; ks < 8; ++ks){
    if (ks < 7){
      int nb = buf ^ 1;
      short* ab = &Asm[nb][0]; short* bb = &Bsm[nb][0];
      int kk = (ks + 1) * 64;
      #pragma unroll
      for (int j = 0; j < 2; ++j){ GLL16(asrcp[j] + kk, ab + aoff[j]); GLL16(bsrcp[j] + kk, bb + boff[j]); }
      asm volatile("s_waitcnt vmcnt(4)" ::: "memory");
    } else {
      asm volatile("s_waitcnt vmcnt(0)" ::: "memory");
    }
    __builtin_amdgcn_s_barrier();

    s16x8 af[2][2], bf[2][2];
    #pragma unroll
    for (int mi = 0; mi < 2; ++mi){
      int row = wm * 32 + mi * 16 + lr;
      #pragma unroll
      for (int s = 0; s < 2; ++s)
        af[mi][s] = *(const s16x8*)&Asm[buf][row * 64 + ((4 * s + lg) ^ (row & 7)) * 8];
    }
    #pragma unroll
    for (int ni = 0; ni < 2; ++ni){
      int row = wn * 32 + ni * 16 + lr;
      #pragma unroll
      for (int s = 0; s < 2; ++s)
        bf[ni][s] = *(const s16x8*)&Bsm[buf][row * 64 + ((4 * s + lg) ^ (row & 7)) * 8];
    }
    #pragma unroll
    for (int s = 0; s < 2; ++s)
      #pragma unroll
      for (int mi = 0; mi < 2; ++mi)
        #pragma unroll
        for (int ni = 0; ni < 2; ++ni)
          acc[mi][ni] = mfma16(af[mi][s], bf[ni][s], acc[mi][ni]);
    __builtin_amdgcn_s_barrier();
    buf ^= 1;
  }

  #pragma unroll
  for (int mi = 0; mi < 2; ++mi)
    #pragma unroll
    for (int ni = 0; ni < 2; ++ni)
      #pragma unroll
      for (int r = 0; r < 4; ++r){
        int row = m0 + wm * 32 + mi * 16 + 4 * lg + r;
        int col = n0 + wn * 32 + ni * 16 + lr;
        C[(size_t)row * DM + col] = acc[mi][ni][r];
      }
}

extern "C" void kernel_launch(void* const* d_in, const int* in_sizes, int n_in,
                              void* d_out, int out_size, void* d_ws, size_t ws_size,
                              hipStream_t stream) {
  const float* x     = (const float*)d_in[0];
  const float* Wq    = (const float*)d_in[1];
  const float* Wk    = (const float*)d_in[2];
  const float* Wv    = (const float*)d_in[3];
  const float* Wo    = (const float*)d_in[4];
  const float* labsK = (const float*)d_in[5];

  char* w = (char*)d_ws;
  short* Wt    = (short*)(w);                                  // 2 MB
  short* xeu   = (short*)(w + (2ull  << 20));                  // 4 MB
  float* Opart = (float*)(w + (6ull  << 20));                  // 20 MB
  float* Mpart = (float*)(w + (26ull << 20));                  // 320 KB
  float* Lpart = (float*)(w + (27ull << 20));                  // 320 KB
  short* Qs    = (short*)(w + (30ull << 20));                  // 4 MB
  short* Ks    = (short*)(w + (34ull << 20));                  // 4 MB
  short* Vt    = (short*)(w + (38ull << 20));                  // 4 MB
  float* Qt    = (float*)(w + (42ull << 20));                  // 128 KB
  float* Kt    = (float*)(w + (42ull << 20) + (128ull << 10)); // 128 KB
  short* Obf   = (short*)(w + (42ull << 20) + (256ull << 10)); // 4 MB

  prep_kernel<<<dim3(2304), 256, 0, stream>>>(Wq, Wk, Wv, Wo, Wt, x, xeu);

  gemm_fused_kernel<<<dim3(8, 32, 3), 256, 0, stream>>>(
      xeu, Wt, labsK, Qt, Qs, Kt, Ks, Vt);

  attn_kernel<<<dim3(640), 256, 0, stream>>>(Qs, Qt, Ks, Kt, Vt, Mpart, Lpart, Opart);

  combine_kernel<<<dim3(1024), 256, 0, stream>>>(Mpart, Lpart, Opart, Obf);

  gemm_o_kernel<<<dim3(8, 64), 256, 0, stream>>>(Obf, Wt + 3 * DM * DM, (float*)d_out);
}